// Round 7
// baseline (810.327 us; speedup 1.0000x reference)
//
#include <hip/hip_runtime.h>
#include <hip/hip_bf16.h>

#define BB 8
#define NN 9216       // 96*96
#define BN 73728      // BB*NN
#define CC 512
#define MM 128
#define DD 256
#define KK 300
#define DK 556        // DD+KK
#define PS 256        // P row: 256 query f32 (vote fused into proj, local in localbf)

typedef __attribute__((ext_vector_type(8))) __bf16 bf16x8;
typedef __attribute__((ext_vector_type(4))) __bf16 bf16x4;
typedef __attribute__((ext_vector_type(4))) float f32x4;

__device__ __forceinline__ void lds_load16(const void* g, void* l) {
    __builtin_amdgcn_global_load_lds(
        (const __attribute__((address_space(1))) unsigned int*)g,
        (__attribute__((address_space(3))) unsigned int*)l, 16, 0, 0);
}

__device__ __forceinline__ bf16x8 combine8(bf16x4 a, bf16x4 b) {
    bf16x8 r;
    r[0] = a[0]; r[1] = a[1]; r[2] = a[2]; r[3] = a[3];
    r[4] = b[0]; r[5] = b[1]; r[6] = b[2]; r[7] = b[3];
    return r;
}

// ---------------- pack [Wv | Wt | Wql]^T into WcatT[640][512] bf16 + bias[640] f32 ----------------
__global__ __launch_bounds__(256) void pack_wt(const float* __restrict__ Wv, const float* __restrict__ bv,
                                               const float* __restrict__ Wt, const float* __restrict__ bt,
                                               const float* __restrict__ Wql,
                                               __bf16* __restrict__ WcatT, float* __restrict__ bias) {
    int gid = blockIdx.x * 256 + threadIdx.x;   // gid = n*512 + k
    if (gid < 640 * 512) {
        int n = gid >> 9, k = gid & 511;
        float v;
        if (n < 128)       v = Wv[k * 128 + n];
        else if (n < 384)  v = Wt[k * 256 + (n - 128)];
        else               v = Wql[k * 256 + (n - 384)];
        WcatT[gid] = (__bf16)v;
    }
    if (gid < 640) {
        bias[gid] = (gid < 128) ? bv[gid] : ((gid < 384) ? bt[gid - 128] : 0.0f);
    }
}

// ---------------- cast x (fp32) -> xb (bf16) ----------------
__global__ __launch_bounds__(256) void cast_x(const float* __restrict__ x, __bf16* __restrict__ xb) {
    long total = (long)BN * CC;
    for (long i = ((long)blockIdx.x * 256 + threadIdx.x) * 8; i < total; i += (long)gridDim.x * 256 * 8) {
        float4 a = *(const float4*)&x[i];
        float4 b = *(const float4*)&x[i + 4];
        bf16x8 o;
        o[0] = (__bf16)a.x; o[1] = (__bf16)a.y; o[2] = (__bf16)a.z; o[3] = (__bf16)a.w;
        o[4] = (__bf16)b.x; o[5] = (__bf16)b.y; o[6] = (__bf16)b.z; o[7] = (__bf16)b.w;
        *(bf16x8*)&xb[i] = o;
    }
}

// ---------------- proj: xb @ WcatT^T + bias -> {votebf (softmax fused), localbf bf16, P query f32} ----------------
// grid: dim3(5, 576); 128x128 tile, BK=64, 4 waves
__global__ __launch_bounds__(256, 2) void proj_mfma(const __bf16* __restrict__ xb,
                                                    const __bf16* __restrict__ WcatT,
                                                    const float* __restrict__ bias,
                                                    float* __restrict__ P,
                                                    __bf16* __restrict__ localbf,
                                                    __bf16* __restrict__ votebf) {
    __shared__ __align__(16) __bf16 Al[128 * 64];
    __shared__ __align__(16) __bf16 Bl[128 * 64];
    int t = threadIdx.x, w = t >> 6, l = t & 63;
    int lo = l & 15, hi = l >> 4;
    int wr = w >> 1, wc = w & 1;
    int n0 = blockIdx.x * 128;
    long row0 = (long)blockIdx.y * 128;

    f32x4 acc[4][4];
    #pragma unroll
    for (int m = 0; m < 4; m++)
        #pragma unroll
        for (int n = 0; n < 4; n++) acc[m][n] = (f32x4){0.f, 0.f, 0.f, 0.f};

    int lrow = l >> 3, lcol = (l & 7) * 8;
    for (int k0 = 0; k0 < 512; k0 += 64) {
        __syncthreads();
        #pragma unroll
        for (int i = 0; i < 4; i++) {
            int c = w * 4 + i;
            lds_load16(xb + (row0 + c * 8 + lrow) * (long)CC + k0 + lcol,
                       (char*)Al + c * 1024);
            lds_load16(WcatT + (long)(n0 + c * 8 + lrow) * CC + k0 + lcol,
                       (char*)Bl + c * 1024);
        }
        __syncthreads();
        #pragma unroll
        for (int ks = 0; ks < 2; ks++) {
            bf16x8 af[4], bfr[4];
            #pragma unroll
            for (int m = 0; m < 4; m++)
                af[m] = *(const bf16x8*)&Al[(wr * 64 + m * 16 + lo) * 64 + ks * 32 + hi * 8];
            #pragma unroll
            for (int n = 0; n < 4; n++)
                bfr[n] = *(const bf16x8*)&Bl[(wc * 64 + n * 16 + lo) * 64 + ks * 32 + hi * 8];
            #pragma unroll
            for (int m = 0; m < 4; m++)
                #pragma unroll
                for (int n = 0; n < 4; n++)
                    acc[m][n] = __builtin_amdgcn_mfma_f32_16x16x32_bf16(af[m], bfr[n], acc[m][n], 0, 0, 0);
        }
    }

    float bv4[4];
    #pragma unroll
    for (int n = 0; n < 4; n++) bv4[n] = bias[n0 + wc * 64 + n * 16 + lo];

    if (n0 == 0) {
        // fused vote softmax over 128 cols per row; rows split by wr, cols split by wc
        __shared__ float RedM[128][2];
        __shared__ float RedS[128][2];
        float gmax[4][4], gsum[4][4];
        #pragma unroll
        for (int m = 0; m < 4; m++)
            #pragma unroll
            for (int r = 0; r < 4; r++) {
                float pm = acc[m][0][r] + bv4[0];
                #pragma unroll
                for (int n = 1; n < 4; n++) pm = fmaxf(pm, acc[m][n][r] + bv4[n]);
                #pragma unroll
                for (int off = 1; off < 16; off <<= 1) pm = fmaxf(pm, __shfl_xor(pm, off));
                gmax[m][r] = pm;
                RedM[wr * 64 + m * 16 + hi * 4 + r][wc] = pm;
            }
        __syncthreads();
        #pragma unroll
        for (int m = 0; m < 4; m++)
            #pragma unroll
            for (int r = 0; r < 4; r++) {
                int rl = wr * 64 + m * 16 + hi * 4 + r;
                gmax[m][r] = fmaxf(RedM[rl][0], RedM[rl][1]);
                float ps = 0.f;
                #pragma unroll
                for (int n = 0; n < 4; n++) ps += __expf(acc[m][n][r] + bv4[n] - gmax[m][r]);
                #pragma unroll
                for (int off = 1; off < 16; off <<= 1) ps += __shfl_xor(ps, off);
                gsum[m][r] = ps;
                RedS[rl][wc] = ps;
            }
        __syncthreads();
        #pragma unroll
        for (int m = 0; m < 4; m++)
            #pragma unroll
            for (int r = 0; r < 4; r++) {
                int rl = wr * 64 + m * 16 + hi * 4 + r;
                float rinv = 1.0f / (RedS[rl][0] + RedS[rl][1]);
                long grow = row0 + rl;
                #pragma unroll
                for (int n = 0; n < 4; n++)
                    votebf[grow * 128 + wc * 64 + n * 16 + lo] =
                        (__bf16)(__expf(acc[m][n][r] + bv4[n] - gmax[m][r]) * rinv);
            }
    } else {
        #pragma unroll
        for (int m = 0; m < 4; m++)
            #pragma unroll
            for (int n = 0; n < 4; n++)
                #pragma unroll
                for (int r = 0; r < 4; r++) {
                    long row = row0 + wr * 64 + m * 16 + hi * 4 + r;
                    int col = n0 + wc * 64 + n * 16 + lo;
                    float v = acc[m][n][r] + bv4[n];
                    if (n0 < 384) localbf[row * 256 + (col - 128)] = (__bf16)v;   // local, bf16
                    else          P[row * PS + (col - 384)] = v;                  // query, f32
                }
    }
}

// ---------------- node[b][128][256] += vote^T @ local  (bf16 MFMA, transposed LDS staging) ----------------
// grid: 8 b x 36 slices (256 n each); 4 waves, wave w owns d-slab [w*64, w*64+64)
__global__ __launch_bounds__(256) void node_mfma(const __bf16* __restrict__ votebf,
                                                 const __bf16* __restrict__ localbf,
                                                 float* __restrict__ node) {
    __shared__ __align__(16) __bf16 Vl[128][68];   // [m][n-chunk 64] +4 pad
    __shared__ __align__(16) __bf16 Ll[256][68];   // [d][n-chunk 64] +4 pad
    int t = threadIdx.x, w = t >> 6, l = t & 63;
    int lo = l & 15, hi = l >> 4;
    int b = blockIdx.x / 36, slice = blockIdx.x % 36;
    long base = (long)b * NN + slice * 256;

    f32x4 acc[8][4];
    #pragma unroll
    for (int mt = 0; mt < 8; mt++)
        #pragma unroll
        for (int dt = 0; dt < 4; dt++) acc[mt][dt] = (f32x4){0.f, 0.f, 0.f, 0.f};

    int mcol = t & 127, qh = t >> 7;
    for (int c0 = 0; c0 < 256; c0 += 64) {
        __syncthreads();
        #pragma unroll
        for (int j = 0; j < 8; j++) {
            int q = j * 2 + qh;
            long n = base + c0 + q * 4;
            bf16x4 pk;
            pk[0] = votebf[n * 128 + mcol];
            pk[1] = votebf[(n + 1) * 128 + mcol];
            pk[2] = votebf[(n + 2) * 128 + mcol];
            pk[3] = votebf[(n + 3) * 128 + mcol];
            *(bf16x4*)&Vl[mcol][q * 4] = pk;
        }
        #pragma unroll
        for (int q = 0; q < 16; q++) {
            long n = base + c0 + q * 4;
            bf16x4 pk;
            pk[0] = localbf[n * 256 + t];
            pk[1] = localbf[(n + 1) * 256 + t];
            pk[2] = localbf[(n + 2) * 256 + t];
            pk[3] = localbf[(n + 3) * 256 + t];
            *(bf16x4*)&Ll[t][q * 4] = pk;
        }
        __syncthreads();
        #pragma unroll
        for (int ks = 0; ks < 2; ks++) {
            bf16x8 bfr[4];
            #pragma unroll
            for (int dt = 0; dt < 4; dt++)
                bfr[dt] = combine8(*(const bf16x4*)&Ll[w * 64 + dt * 16 + lo][ks * 32 + hi * 8],
                                   *(const bf16x4*)&Ll[w * 64 + dt * 16 + lo][ks * 32 + hi * 8 + 4]);
            #pragma unroll
            for (int mt = 0; mt < 8; mt++) {
                bf16x8 A = combine8(*(const bf16x4*)&Vl[mt * 16 + lo][ks * 32 + hi * 8],
                                    *(const bf16x4*)&Vl[mt * 16 + lo][ks * 32 + hi * 8 + 4]);
                #pragma unroll
                for (int dt = 0; dt < 4; dt++)
                    acc[mt][dt] = __builtin_amdgcn_mfma_f32_16x16x32_bf16(A, bfr[dt], acc[mt][dt], 0, 0, 0);
            }
        }
    }
    #pragma unroll
    for (int mt = 0; mt < 8; mt++)
        #pragma unroll
        for (int dt = 0; dt < 4; dt++)
            #pragma unroll
            for (int r = 0; r < 4; r++)
                unsafeAtomicAdd(&node[((long)b * MM + mt * 16 + hi * 4 + r) * DD + w * 64 + dt * 16 + lo],
                                acc[mt][dt][r]);
}

// ---------------- gcn[b][m][:] = [node_row | emb_row] @ Wg + bg ----------------
__global__ __launch_bounds__(256) void gcn_dense(const float* __restrict__ node, const float* __restrict__ emb,
                                                 const float* __restrict__ Wg, const float* __restrict__ bg,
                                                 float* __restrict__ gcn) {
    __shared__ float a[DK];
    int b = blockIdx.x >> 7, m = blockIdx.x & 127, t = threadIdx.x;
    for (int i = t; i < DK; i += 256)
        a[i] = (i < DD) ? node[(b * MM + m) * DD + i] : emb[m * KK + (i - DD)];
    __syncthreads();
    float acc = bg[t];
    for (int k = 0; k < DK; k++) acc += a[k] * Wg[k * DD + t];
    gcn[(b * MM + m) * DD + t] = acc;
}

// ---------------- evolved = relu(norm_adj @ gcn) ----------------
__global__ __launch_bounds__(256) void gcn_adj_relu(const float* __restrict__ adj, const float* __restrict__ gcn,
                                                    float* __restrict__ evo) {
    __shared__ float ar[128];
    int b = blockIdx.x >> 7, m = blockIdx.x & 127, t = threadIdx.x;
    if (t < 128) ar[t] = adj[m * MM + t];
    __syncthreads();
    float acc = 0.0f;
    for (int k = 0; k < MM; k++) acc += ar[k] * gcn[(b * MM + k) * DD + t];
    evo[(b * MM + m) * DD + t] = fmaxf(acc, 0.0f);
}

// ---------------- Kbf[b][128][256] (bf16) = evolved @ Wkn ----------------
__global__ __launch_bounds__(256) void keyv_k(const float* __restrict__ evo, const float* __restrict__ Wkn,
                                              __bf16* __restrict__ Kbf) {
    __shared__ float e[DD];
    int b = blockIdx.x >> 7, m = blockIdx.x & 127, t = threadIdx.x;
    e[t] = evo[(b * MM + m) * DD + t];
    __syncthreads();
    float acc = 0.0f;
    for (int k = 0; k < DD; k++) acc += e[k] * Wkn[k * DD + t];
    Kbf[(b * MM + m) * DD + t] = (__bf16)acc;
}

// ---------------- Vt[b][512][128] (bf16, c-major) = (evolved @ Wm + bm)^T ----------------
__global__ __launch_bounds__(512) void values_k(const float* __restrict__ evo, const float* __restrict__ Wm,
                                                const float* __restrict__ bm, __bf16* __restrict__ Vt) {
    __shared__ float e[DD];
    int b = blockIdx.x >> 7, m = blockIdx.x & 127, t = threadIdx.x;
    if (t < DD) e[t] = evo[(b * MM + m) * DD + t];
    __syncthreads();
    float acc = bm[t];
    for (int k = 0; k < DD; k++) acc += e[k] * Wm[k * CC + t];
    Vt[((long)b * CC + t) * MM + m] = (__bf16)acc;
}

// ---------------- fused attention via MFMA bf16; PV split into 2 c-half chunks ----------------
__global__ __launch_bounds__(256, 4) void attn_mfma(const float* __restrict__ P,
                                                    const __bf16* __restrict__ Kbf,
                                                    const __bf16* __restrict__ Vt,
                                                    const float* __restrict__ x,
                                                    float* __restrict__ out) {
    __shared__ __align__(16) __bf16 Pl[4][16][136];
    int t = threadIdx.x;
    int w = t >> 6, l = t & 63;
    int lo = l & 15, hi = l >> 4;
    int b = blockIdx.x / 144, tile = blockIdx.x % 144;
    int n0 = tile * 64;
    long brow = (long)b * NN;
    long qrow = brow + n0 + w * 16 + lo;
    const float* Pq = P + qrow * PS;
    const __bf16* Kb = Kbf + (long)b * MM * DD;
    const __bf16* Vb = Vt + (long)b * CC * MM;

    f32x4 S[8];
    #pragma unroll
    for (int i = 0; i < 8; i++) S[i] = (f32x4){0.f, 0.f, 0.f, 0.f};

    #pragma unroll
    for (int k0 = 0; k0 < 8; k0++) {
        float4 qa = *(const float4*)(Pq + k0 * 32 + hi * 8);
        float4 qb = *(const float4*)(Pq + k0 * 32 + hi * 8 + 4);
        bf16x8 A;
        A[0] = (__bf16)qa.x; A[1] = (__bf16)qa.y; A[2] = (__bf16)qa.z; A[3] = (__bf16)qa.w;
        A[4] = (__bf16)qb.x; A[5] = (__bf16)qb.y; A[6] = (__bf16)qb.z; A[7] = (__bf16)qb.w;
        #pragma unroll
        for (int mt = 0; mt < 8; mt++) {
            bf16x8 Bf = *(const bf16x8*)(Kb + (mt * 16 + lo) * DD + k0 * 32 + hi * 8);
            S[mt] = __builtin_amdgcn_mfma_f32_16x16x32_bf16(A, Bf, S[mt], 0, 0, 0);
        }
    }

    float mx[4], sm[4], rs[4];
    #pragma unroll
    for (int r = 0; r < 4; r++) {
        float m0 = S[0][r];
        #pragma unroll
        for (int mt = 1; mt < 8; mt++) m0 = fmaxf(m0, S[mt][r]);
        #pragma unroll
        for (int off = 1; off < 16; off <<= 1) m0 = fmaxf(m0, __shfl_xor(m0, off));
        mx[r] = m0;
    }
    #pragma unroll
    for (int r = 0; r < 4; r++) sm[r] = 0.f;
    #pragma unroll
    for (int mt = 0; mt < 8; mt++)
        #pragma unroll
        for (int r = 0; r < 4; r++) {
            float e = __expf(S[mt][r] - mx[r]);
            S[mt][r] = e;
            sm[r] += e;
        }
    #pragma unroll
    for (int r = 0; r < 4; r++) {
        float s0 = sm[r];
        #pragma unroll
        for (int off = 1; off < 16; off <<= 1) s0 += __shfl_xor(s0, off);
        rs[r] = 1.0f / s0;
    }
    #pragma unroll
    for (int mt = 0; mt < 8; mt++)
        #pragma unroll
        for (int r = 0; r < 4; r++)
            Pl[w][hi * 4 + r][mt * 16 + lo] = (__bf16)(S[mt][r] * rs[r]);

    // PV in two c-half chunks (O[16] each) to cut register peak -> 4 waves/SIMD
    #pragma unroll 1
    for (int c2 = 0; c2 < 2; c2++) {
        f32x4 O[16];
        #pragma unroll
        for (int i = 0; i < 16; i++) O[i] = (f32x4){0.f, 0.f, 0.f, 0.f};
        #pragma unroll
        for (int mc = 0; mc < 4; mc++) {
            bf16x8 A2 = *(const bf16x8*)&Pl[w][lo][mc * 32 + hi * 8];
            #pragma unroll
            for (int ct = 0; ct < 16; ct++) {
                bf16x8 Bv = *(const bf16x8*)(Vb + (long)(c2 * 256 + ct * 16 + lo) * MM + mc * 32 + hi * 8);
                O[ct] = __builtin_amdgcn_mfma_f32_16x16x32_bf16(A2, Bv, O[ct], 0, 0, 0);
            }
        }
        #pragma unroll
        for (int ct = 0; ct < 16; ct++) {
            #pragma unroll
            for (int r = 0; r < 4; r++) {
                long gi = (brow + n0 + w * 16 + hi * 4 + r) * (long)CC + c2 * 256 + ct * 16 + lo;
                out[gi] = fmaxf(x[gi] + O[ct][r], 0.f);
            }
        }
    }
}

extern "C" void kernel_launch(void* const* d_in, const int* in_sizes, int n_in,
                              void* d_out, int out_size, void* d_ws, size_t ws_size,
                              hipStream_t stream) {
    const float* x    = (const float*)d_in[0];
    const float* adj  = (const float*)d_in[1];
    const float* emb  = (const float*)d_in[2];
    const float* Wv   = (const float*)d_in[3];
    const float* bv   = (const float*)d_in[4];
    const float* Wt   = (const float*)d_in[5];
    const float* bt   = (const float*)d_in[6];
    const float* Wg   = (const float*)d_in[7];
    const float* bg   = (const float*)d_in[8];
    const float* Wql  = (const float*)d_in[9];
    const float* Wkn  = (const float*)d_in[10];
    const float* Wm   = (const float*)d_in[11];
    const float* bm   = (const float*)d_in[12];
    float* out = (float*)d_out;

    float* ws      = (float*)d_ws;
    __bf16* WcatT  = (__bf16*)ws;                                 // 640*512 bf16
    float* bias    = (float*)(WcatT + 640 * 512);                 // 640 f32
    float* P       = bias + 640;                                  // [BN][256] f32 query
    __bf16* localbf = (__bf16*)(P + (long)BN * PS);               // [BN][256] bf16
    __bf16* votebf  = localbf + (long)BN * 256;                   // [BN][128] bf16
    float* node    = (float*)(votebf + (long)BN * 128);           // [8][128][256] f32
    float* gcn     = node + BB * MM * DD;
    float* evo     = gcn + BB * MM * DD;
    __bf16* Kbf    = (__bf16*)(evo + BB * MM * DD);               // [8][128][256] bf16
    __bf16* Vt     = Kbf + (long)BB * MM * DD;                    // [8][512][128] bf16
    __bf16* xb     = (__bf16*)d_out;                              // scratch: dead until attn overwrites

    pack_wt<<<1280, 256, 0, stream>>>(Wv, bv, Wt, bt, Wql, WcatT, bias);
    cast_x<<<2048, 256, 0, stream>>>(x, xb);
    proj_mfma<<<dim3(5, 576), 256, 0, stream>>>(xb, WcatT, bias, P, localbf, votebf);
    hipMemsetAsync(node, 0, (size_t)BB * MM * DD * sizeof(float), stream);
    node_mfma<<<BB * 36, 256, 0, stream>>>(votebf, localbf, node);
    gcn_dense<<<BB * MM, 256, 0, stream>>>(node, emb, Wg, bg, gcn);
    gcn_adj_relu<<<BB * MM, 256, 0, stream>>>(adj, gcn, evo);
    keyv_k<<<BB * MM, 256, 0, stream>>>(evo, Wkn, Kbf);
    values_k<<<BB * MM, 512, 0, stream>>>(evo, Wm, bm, Vt);
    attn_mfma<<<BB * 144, 256, 0, stream>>>(P, Kbf, Vt, x, out);
}

// Round 8
// 672.106 us; speedup vs baseline: 1.2057x; 1.2057x over previous
//
#include <hip/hip_runtime.h>
#include <hip/hip_bf16.h>

#define BB 8
#define NN 9216       // 96*96
#define BN 73728      // BB*NN
#define CC 512
#define MM 128
#define DD 256
#define KK 300
#define DK 556        // DD+KK
#define PS 256        // P row: 256 query f32 (vote fused into proj, local in localbf)

typedef __attribute__((ext_vector_type(8))) __bf16 bf16x8;
typedef __attribute__((ext_vector_type(4))) __bf16 bf16x4;
typedef __attribute__((ext_vector_type(4))) float f32x4;

__device__ __forceinline__ void lds_load16(const void* g, void* l) {
    __builtin_amdgcn_global_load_lds(
        (const __attribute__((address_space(1))) unsigned int*)g,
        (__attribute__((address_space(3))) unsigned int*)l, 16, 0, 0);
}

__device__ __forceinline__ bf16x8 combine8(bf16x4 a, bf16x4 b) {
    bf16x8 r;
    r[0] = a[0]; r[1] = a[1]; r[2] = a[2]; r[3] = a[3];
    r[4] = b[0]; r[5] = b[1]; r[6] = b[2]; r[7] = b[3];
    return r;
}

// ---------------- pack [Wv | Wt | Wql]^T into WcatT[640][512] bf16 + bias[640] f32 ----------------
__global__ __launch_bounds__(256) void pack_wt(const float* __restrict__ Wv, const float* __restrict__ bv,
                                               const float* __restrict__ Wt, const float* __restrict__ bt,
                                               const float* __restrict__ Wql,
                                               __bf16* __restrict__ WcatT, float* __restrict__ bias) {
    int gid = blockIdx.x * 256 + threadIdx.x;   // gid = n*512 + k
    if (gid < 640 * 512) {
        int n = gid >> 9, k = gid & 511;
        float v;
        if (n < 128)       v = Wv[k * 128 + n];
        else if (n < 384)  v = Wt[k * 256 + (n - 128)];
        else               v = Wql[k * 256 + (n - 384)];
        WcatT[gid] = (__bf16)v;
    }
    if (gid < 640) {
        bias[gid] = (gid < 128) ? bv[gid] : ((gid < 384) ? bt[gid - 128] : 0.0f);
    }
}

// ---------------- cast x (fp32) -> xb (bf16) ----------------
__global__ __launch_bounds__(256) void cast_x(const float* __restrict__ x, __bf16* __restrict__ xb) {
    long total = (long)BN * CC;
    for (long i = ((long)blockIdx.x * 256 + threadIdx.x) * 8; i < total; i += (long)gridDim.x * 256 * 8) {
        float4 a = *(const float4*)&x[i];
        float4 b = *(const float4*)&x[i + 4];
        bf16x8 o;
        o[0] = (__bf16)a.x; o[1] = (__bf16)a.y; o[2] = (__bf16)a.z; o[3] = (__bf16)a.w;
        o[4] = (__bf16)b.x; o[5] = (__bf16)b.y; o[6] = (__bf16)b.z; o[7] = (__bf16)b.w;
        *(bf16x8*)&xb[i] = o;
    }
}

// ---------------- proj: xb @ WcatT^T + bias -> {votebf (softmax fused), localbf bf16, P query f32} ----------------
// grid: dim3(5, 576); 128x128 tile, BK=64, 4 waves
__global__ __launch_bounds__(256, 2) void proj_mfma(const __bf16* __restrict__ xb,
                                                    const __bf16* __restrict__ WcatT,
                                                    const float* __restrict__ bias,
                                                    float* __restrict__ P,
                                                    __bf16* __restrict__ localbf,
                                                    __bf16* __restrict__ votebf) {
    __shared__ __align__(16) __bf16 Al[128 * 64];
    __shared__ __align__(16) __bf16 Bl[128 * 64];
    int t = threadIdx.x, w = t >> 6, l = t & 63;
    int lo = l & 15, hi = l >> 4;
    int wr = w >> 1, wc = w & 1;
    int n0 = blockIdx.x * 128;
    long row0 = (long)blockIdx.y * 128;

    f32x4 acc[4][4];
    #pragma unroll
    for (int m = 0; m < 4; m++)
        #pragma unroll
        for (int n = 0; n < 4; n++) acc[m][n] = (f32x4){0.f, 0.f, 0.f, 0.f};

    int lrow = l >> 3, lcol = (l & 7) * 8;
    for (int k0 = 0; k0 < 512; k0 += 64) {
        __syncthreads();
        #pragma unroll
        for (int i = 0; i < 4; i++) {
            int c = w * 4 + i;
            lds_load16(xb + (row0 + c * 8 + lrow) * (long)CC + k0 + lcol,
                       (char*)Al + c * 1024);
            lds_load16(WcatT + (long)(n0 + c * 8 + lrow) * CC + k0 + lcol,
                       (char*)Bl + c * 1024);
        }
        __syncthreads();
        #pragma unroll
        for (int ks = 0; ks < 2; ks++) {
            bf16x8 af[4], bfr[4];
            #pragma unroll
            for (int m = 0; m < 4; m++)
                af[m] = *(const bf16x8*)&Al[(wr * 64 + m * 16 + lo) * 64 + ks * 32 + hi * 8];
            #pragma unroll
            for (int n = 0; n < 4; n++)
                bfr[n] = *(const bf16x8*)&Bl[(wc * 64 + n * 16 + lo) * 64 + ks * 32 + hi * 8];
            #pragma unroll
            for (int m = 0; m < 4; m++)
                #pragma unroll
                for (int n = 0; n < 4; n++)
                    acc[m][n] = __builtin_amdgcn_mfma_f32_16x16x32_bf16(af[m], bfr[n], acc[m][n], 0, 0, 0);
        }
    }

    float bv4[4];
    #pragma unroll
    for (int n = 0; n < 4; n++) bv4[n] = bias[n0 + wc * 64 + n * 16 + lo];

    if (n0 == 0) {
        // fused vote softmax over 128 cols per row; rows split by wr, cols split by wc
        __shared__ float RedM[128][2];
        __shared__ float RedS[128][2];
        float gmax[4][4];
        #pragma unroll
        for (int m = 0; m < 4; m++)
            #pragma unroll
            for (int r = 0; r < 4; r++) {
                float pm = acc[m][0][r] + bv4[0];
                #pragma unroll
                for (int n = 1; n < 4; n++) pm = fmaxf(pm, acc[m][n][r] + bv4[n]);
                #pragma unroll
                for (int off = 1; off < 16; off <<= 1) pm = fmaxf(pm, __shfl_xor(pm, off));
                RedM[wr * 64 + m * 16 + hi * 4 + r][wc] = pm;
            }
        __syncthreads();
        #pragma unroll
        for (int m = 0; m < 4; m++)
            #pragma unroll
            for (int r = 0; r < 4; r++) {
                int rl = wr * 64 + m * 16 + hi * 4 + r;
                gmax[m][r] = fmaxf(RedM[rl][0], RedM[rl][1]);
                float ps = 0.f;
                #pragma unroll
                for (int n = 0; n < 4; n++) ps += __expf(acc[m][n][r] + bv4[n] - gmax[m][r]);
                #pragma unroll
                for (int off = 1; off < 16; off <<= 1) ps += __shfl_xor(ps, off);
                RedS[rl][wc] = ps;
            }
        __syncthreads();
        #pragma unroll
        for (int m = 0; m < 4; m++)
            #pragma unroll
            for (int r = 0; r < 4; r++) {
                int rl = wr * 64 + m * 16 + hi * 4 + r;
                float rinv = 1.0f / (RedS[rl][0] + RedS[rl][1]);
                long grow = row0 + rl;
                #pragma unroll
                for (int n = 0; n < 4; n++)
                    votebf[grow * 128 + wc * 64 + n * 16 + lo] =
                        (__bf16)(__expf(acc[m][n][r] + bv4[n] - gmax[m][r]) * rinv);
            }
    } else {
        #pragma unroll
        for (int m = 0; m < 4; m++)
            #pragma unroll
            for (int n = 0; n < 4; n++)
                #pragma unroll
                for (int r = 0; r < 4; r++) {
                    long row = row0 + wr * 64 + m * 16 + hi * 4 + r;
                    int col = n0 + wc * 64 + n * 16 + lo;
                    float v = acc[m][n][r] + bv4[n];
                    if (n0 < 384) localbf[row * 256 + (col - 128)] = (__bf16)v;   // local, bf16
                    else          P[row * PS + (col - 384)] = v;                  // query, f32
                }
    }
}

// ---------------- node[b][128][256] += vote^T @ local  (bf16 MFMA, transposed LDS staging) ----------------
// grid: 8 b x 36 slices (256 n each); 4 waves, wave w owns d-slab [w*64, w*64+64)
__global__ __launch_bounds__(256) void node_mfma(const __bf16* __restrict__ votebf,
                                                 const __bf16* __restrict__ localbf,
                                                 float* __restrict__ node) {
    __shared__ __align__(16) __bf16 Vl[128][68];   // [m][n-chunk 64] +4 pad
    __shared__ __align__(16) __bf16 Ll[256][68];   // [d][n-chunk 64] +4 pad
    int t = threadIdx.x, w = t >> 6, l = t & 63;
    int lo = l & 15, hi = l >> 4;
    int b = blockIdx.x / 36, slice = blockIdx.x % 36;
    long base = (long)b * NN + slice * 256;

    f32x4 acc[8][4];
    #pragma unroll
    for (int mt = 0; mt < 8; mt++)
        #pragma unroll
        for (int dt = 0; dt < 4; dt++) acc[mt][dt] = (f32x4){0.f, 0.f, 0.f, 0.f};

    int mcol = t & 127, qh = t >> 7;
    for (int c0 = 0; c0 < 256; c0 += 64) {
        __syncthreads();
        #pragma unroll
        for (int j = 0; j < 8; j++) {
            int q = j * 2 + qh;
            long n = base + c0 + q * 4;
            bf16x4 pk;
            pk[0] = votebf[n * 128 + mcol];
            pk[1] = votebf[(n + 1) * 128 + mcol];
            pk[2] = votebf[(n + 2) * 128 + mcol];
            pk[3] = votebf[(n + 3) * 128 + mcol];
            *(bf16x4*)&Vl[mcol][q * 4] = pk;
        }
        #pragma unroll
        for (int q = 0; q < 16; q++) {
            long n = base + c0 + q * 4;
            bf16x4 pk;
            pk[0] = localbf[n * 256 + t];
            pk[1] = localbf[(n + 1) * 256 + t];
            pk[2] = localbf[(n + 2) * 256 + t];
            pk[3] = localbf[(n + 3) * 256 + t];
            *(bf16x4*)&Ll[t][q * 4] = pk;
        }
        __syncthreads();
        #pragma unroll
        for (int ks = 0; ks < 2; ks++) {
            bf16x8 bfr[4];
            #pragma unroll
            for (int dt = 0; dt < 4; dt++)
                bfr[dt] = combine8(*(const bf16x4*)&Ll[w * 64 + dt * 16 + lo][ks * 32 + hi * 8],
                                   *(const bf16x4*)&Ll[w * 64 + dt * 16 + lo][ks * 32 + hi * 8 + 4]);
            #pragma unroll
            for (int mt = 0; mt < 8; mt++) {
                bf16x8 A = combine8(*(const bf16x4*)&Vl[mt * 16 + lo][ks * 32 + hi * 8],
                                    *(const bf16x4*)&Vl[mt * 16 + lo][ks * 32 + hi * 8 + 4]);
                #pragma unroll
                for (int dt = 0; dt < 4; dt++)
                    acc[mt][dt] = __builtin_amdgcn_mfma_f32_16x16x32_bf16(A, bfr[dt], acc[mt][dt], 0, 0, 0);
            }
        }
    }
    #pragma unroll
    for (int mt = 0; mt < 8; mt++)
        #pragma unroll
        for (int dt = 0; dt < 4; dt++)
            #pragma unroll
            for (int r = 0; r < 4; r++)
                unsafeAtomicAdd(&node[((long)b * MM + mt * 16 + hi * 4 + r) * DD + w * 64 + dt * 16 + lo],
                                acc[mt][dt][r]);
}

// ---------------- gcn[b][m][:] = [node_row | emb_row] @ Wg + bg ----------------
__global__ __launch_bounds__(256) void gcn_dense(const float* __restrict__ node, const float* __restrict__ emb,
                                                 const float* __restrict__ Wg, const float* __restrict__ bg,
                                                 float* __restrict__ gcn) {
    __shared__ float a[DK];
    int b = blockIdx.x >> 7, m = blockIdx.x & 127, t = threadIdx.x;
    for (int i = t; i < DK; i += 256)
        a[i] = (i < DD) ? node[(b * MM + m) * DD + i] : emb[m * KK + (i - DD)];
    __syncthreads();
    float acc = bg[t];
    for (int k = 0; k < DK; k++) acc += a[k] * Wg[k * DD + t];
    gcn[(b * MM + m) * DD + t] = acc;
}

// ---------------- evolved = relu(norm_adj @ gcn) ----------------
__global__ __launch_bounds__(256) void gcn_adj_relu(const float* __restrict__ adj, const float* __restrict__ gcn,
                                                    float* __restrict__ evo) {
    __shared__ float ar[128];
    int b = blockIdx.x >> 7, m = blockIdx.x & 127, t = threadIdx.x;
    if (t < 128) ar[t] = adj[m * MM + t];
    __syncthreads();
    float acc = 0.0f;
    for (int k = 0; k < MM; k++) acc += ar[k] * gcn[(b * MM + k) * DD + t];
    evo[(b * MM + m) * DD + t] = fmaxf(acc, 0.0f);
}

// ---------------- Kbf[b][128][256] (bf16) = evolved @ Wkn ----------------
__global__ __launch_bounds__(256) void keyv_k(const float* __restrict__ evo, const float* __restrict__ Wkn,
                                              __bf16* __restrict__ Kbf) {
    __shared__ float e[DD];
    int b = blockIdx.x >> 7, m = blockIdx.x & 127, t = threadIdx.x;
    e[t] = evo[(b * MM + m) * DD + t];
    __syncthreads();
    float acc = 0.0f;
    for (int k = 0; k < DD; k++) acc += e[k] * Wkn[k * DD + t];
    Kbf[(b * MM + m) * DD + t] = (__bf16)acc;
}

// ---------------- Vt[b][512][128] (bf16, c-major) = (evolved @ Wm + bm)^T ----------------
__global__ __launch_bounds__(512) void values_k(const float* __restrict__ evo, const float* __restrict__ Wm,
                                                const float* __restrict__ bm, __bf16* __restrict__ Vt) {
    __shared__ float e[DD];
    int b = blockIdx.x >> 7, m = blockIdx.x & 127, t = threadIdx.x;
    if (t < DD) e[t] = evo[(b * MM + m) * DD + t];
    __syncthreads();
    float acc = bm[t];
    for (int k = 0; k < DD; k++) acc += e[k] * Wm[k * CC + t];
    Vt[((long)b * CC + t) * MM + m] = (__bf16)acc;
}

// ---------------- fused attention via MFMA bf16; ct-outer PV with transient accumulator ----------------
__global__ __launch_bounds__(256, 3) void attn_mfma(const float* __restrict__ P,
                                                    const __bf16* __restrict__ Kbf,
                                                    const __bf16* __restrict__ Vt,
                                                    const float* __restrict__ x,
                                                    float* __restrict__ out) {
    __shared__ __align__(16) __bf16 Pl[4][16][136];
    int t = threadIdx.x;
    int w = t >> 6, l = t & 63;
    int lo = l & 15, hi = l >> 4;
    int b = blockIdx.x / 144, tile = blockIdx.x % 144;
    int n0 = tile * 64;
    long brow = (long)b * NN;
    long qrow = brow + n0 + w * 16 + lo;
    const float* Pq = P + qrow * PS;
    const __bf16* Kb = Kbf + (long)b * MM * DD;
    const __bf16* Vb = Vt + (long)b * CC * MM;

    // ---- QK^T ----
    f32x4 S[8];
    #pragma unroll
    for (int i = 0; i < 8; i++) S[i] = (f32x4){0.f, 0.f, 0.f, 0.f};

    #pragma unroll
    for (int k0 = 0; k0 < 8; k0++) {
        float4 qa = *(const float4*)(Pq + k0 * 32 + hi * 8);
        float4 qb = *(const float4*)(Pq + k0 * 32 + hi * 8 + 4);
        bf16x8 A;
        A[0] = (__bf16)qa.x; A[1] = (__bf16)qa.y; A[2] = (__bf16)qa.z; A[3] = (__bf16)qa.w;
        A[4] = (__bf16)qb.x; A[5] = (__bf16)qb.y; A[6] = (__bf16)qb.z; A[7] = (__bf16)qb.w;
        #pragma unroll
        for (int mt = 0; mt < 8; mt++) {
            bf16x8 Bf = *(const bf16x8*)(Kb + (mt * 16 + lo) * DD + k0 * 32 + hi * 8);
            S[mt] = __builtin_amdgcn_mfma_f32_16x16x32_bf16(A, Bf, S[mt], 0, 0, 0);
        }
    }

    // ---- softmax (rows in regs; 16-lane-group reduce) ----
    float mx[4], sm[4], rs[4];
    #pragma unroll
    for (int r = 0; r < 4; r++) {
        float m0 = S[0][r];
        #pragma unroll
        for (int mt = 1; mt < 8; mt++) m0 = fmaxf(m0, S[mt][r]);
        #pragma unroll
        for (int off = 1; off < 16; off <<= 1) m0 = fmaxf(m0, __shfl_xor(m0, off));
        mx[r] = m0;
    }
    #pragma unroll
    for (int r = 0; r < 4; r++) sm[r] = 0.f;
    #pragma unroll
    for (int mt = 0; mt < 8; mt++)
        #pragma unroll
        for (int r = 0; r < 4; r++) {
            float e = __expf(S[mt][r] - mx[r]);
            S[mt][r] = e;
            sm[r] += e;
        }
    #pragma unroll
    for (int r = 0; r < 4; r++) {
        float s0 = sm[r];
        #pragma unroll
        for (int off = 1; off < 16; off <<= 1) s0 += __shfl_xor(s0, off);
        rs[r] = 1.0f / s0;
    }
    #pragma unroll
    for (int mt = 0; mt < 8; mt++)
        #pragma unroll
        for (int r = 0; r < 4; r++)
            Pl[w][hi * 4 + r][mt * 16 + lo] = (__bf16)(S[mt][r] * rs[r]);

    // ---- PV, ct-outer: transient f32x4 accumulator per c-tile, immediate epilogue ----
    bf16x8 pa[4];
    #pragma unroll
    for (int mc = 0; mc < 4; mc++) pa[mc] = *(const bf16x8*)&Pl[w][lo][mc * 32 + hi * 8];

    long orow = brow + n0 + w * 16 + hi * 4;   // first of this lane's 4 output rows
    #pragma unroll 2
    for (int ct = 0; ct < 32; ct++) {
        f32x4 o = (f32x4){0.f, 0.f, 0.f, 0.f};
        #pragma unroll
        for (int mc = 0; mc < 4; mc++) {
            bf16x8 Bv = *(const bf16x8*)(Vb + (long)(ct * 16 + lo) * MM + mc * 32 + hi * 8);
            o = __builtin_amdgcn_mfma_f32_16x16x32_bf16(pa[mc], Bv, o, 0, 0, 0);
        }
        #pragma unroll
        for (int r = 0; r < 4; r++) {
            long gi = (orow + r) * (long)CC + ct * 16 + lo;
            out[gi] = fmaxf(x[gi] + o[r], 0.f);
        }
    }
}

extern "C" void kernel_launch(void* const* d_in, const int* in_sizes, int n_in,
                              void* d_out, int out_size, void* d_ws, size_t ws_size,
                              hipStream_t stream) {
    const float* x    = (const float*)d_in[0];
    const float* adj  = (const float*)d_in[1];
    const float* emb  = (const float*)d_in[2];
    const float* Wv   = (const float*)d_in[3];
    const float* bv   = (const float*)d_in[4];
    const float* Wt   = (const float*)d_in[5];
    const float* bt   = (const float*)d_in[6];
    const float* Wg   = (const float*)d_in[7];
    const float* bg   = (const float*)d_in[8];
    const float* Wql  = (const float*)d_in[9];
    const float* Wkn  = (const float*)d_in[10];
    const float* Wm   = (const float*)d_in[11];
    const float* bm   = (const float*)d_in[12];
    float* out = (float*)d_out;

    float* ws      = (float*)d_ws;
    __bf16* WcatT  = (__bf16*)ws;                                 // 640*512 bf16
    float* bias    = (float*)(WcatT + 640 * 512);                 // 640 f32
    float* P       = bias + 640;                                  // [BN][256] f32 query
    __bf16* localbf = (__bf16*)(P + (long)BN * PS);               // [BN][256] bf16
    __bf16* votebf  = localbf + (long)BN * 256;                   // [BN][128] bf16
    float* node    = (float*)(votebf + (long)BN * 128);           // [8][128][256] f32
    float* gcn     = node + BB * MM * DD;
    float* evo     = gcn + BB * MM * DD;
    __bf16* Kbf    = (__bf16*)(evo + BB * MM * DD);               // [8][128][256] bf16
    __bf16* Vt     = Kbf + (long)BB * MM * DD;                    // [8][512][128] bf16
    __bf16* xb     = (__bf16*)d_out;                              // scratch: dead until attn overwrites

    pack_wt<<<1280, 256, 0, stream>>>(Wv, bv, Wt, bt, Wql, WcatT, bias);
    cast_x<<<2048, 256, 0, stream>>>(x, xb);
    proj_mfma<<<dim3(5, 576), 256, 0, stream>>>(xb, WcatT, bias, P, localbf, votebf);
    hipMemsetAsync(node, 0, (size_t)BB * MM * DD * sizeof(float), stream);
    node_mfma<<<BB * 36, 256, 0, stream>>>(votebf, localbf, node);
    gcn_dense<<<BB * MM, 256, 0, stream>>>(node, emb, Wg, bg, gcn);
    gcn_adj_relu<<<BB * MM, 256, 0, stream>>>(adj, gcn, evo);
    keyv_k<<<BB * MM, 256, 0, stream>>>(evo, Wkn, Kbf);
    values_k<<<BB * MM, 512, 0, stream>>>(evo, Wm, bm, Vt);
    attn_mfma<<<BB * 144, 256, 0, stream>>>(P, Kbf, Vt, x, out);
}